// Round 9
// baseline (108.238 us; speedup 1.0000x reference)
//
#include <hip/hip_runtime.h>

#define BB 32
#define CC 1024
#define QQ 128
#define EE 512

typedef unsigned int uint32;
typedef unsigned short u16;
typedef __bf16 bf16x8 __attribute__((ext_vector_type(8)));
typedef float f32x4 __attribute__((ext_vector_type(4)));

// workspace layout (bytes)
#define QMF_OFF  (0u)                  // bf16 frag-major: [b][ks16][nf8][lane][8]  (qm' = q*ws_m + ws_c)
#define QTF_OFF  (4u<<20)              // bf16 frag-major: [b][ks2 4][ne32][lane][8]
#define QDP_OFF  (8u<<20)              // f32 [b][et4][128] qdot partials
#define PVB_OFF  ((8u<<20) + 65536u)   // f32 [256 blocks][512] q2c partial
#define MB_OFF   (PVB_OFF + 524288u)   // f32 [256]
#define SB_OFF   (MB_OFF + 1024u)      // f32 [256]

// raw barrier: LDS visibility only — does NOT drain vmcnt (keeps loads/stores in flight)
#define RAWBAR() asm volatile("s_waitcnt lgkmcnt(0)\n\ts_barrier" ::: "memory")

__device__ __forceinline__ u16 bfc(float f){
  __bf16 h = (__bf16)f;                // HW v_cvt (RNE)
  return __builtin_bit_cast(u16, h);
}
__device__ __forceinline__ float bf2f(uint32 lo16){
  return __builtin_bit_cast(float, lo16 << 16);
}

// ---- fused prep: per (b, e-slice et): qm' frags + qt frags + qdot partial ----
__global__ __launch_bounds__(256) void k_prep(const float* __restrict__ q,
                                              const float* __restrict__ ws,
                                              unsigned char* __restrict__ wsp){
  const int b = blockIdx.x >> 2, et = blockIdx.x & 3, e0 = et*128;
  __shared__ u16 tm[128*136];          // qm' = q*ws_m + ws_c (bf16)
  __shared__ u16 tt[128*136];          // raw q (bf16)
  const int tid = threadIdx.x;
  float* qdp = (float*)(wsp + QDP_OFF) + (size_t)(b*4 + et)*128;
  #pragma unroll
  for (int i=0;i<16;i++){
    int id = tid + i*256;
    int qi = id >> 5;
    int el = (id & 31) << 2;
    float4 v = *(const float4*)(q + (size_t)(b*QQ+qi)*EE + e0 + el);
    float4 a = *(const float4*)(ws +          e0 + el);
    float4 c = *(const float4*)(ws +   EE +   e0 + el);
    float4 m = *(const float4*)(ws + 2*EE +   e0 + el);
    ushort4 um; um.x = bfc(v.x*m.x + c.x); um.y = bfc(v.y*m.y + c.y);
                um.z = bfc(v.z*m.z + c.z); um.w = bfc(v.w*m.w + c.w);
    *(ushort4*)&tm[qi*136 + el] = um;
    ushort4 ut; ut.x = bfc(v.x); ut.y = bfc(v.y); ut.z = bfc(v.z); ut.w = bfc(v.w);
    *(ushort4*)&tt[qi*136 + el] = ut;
    float d = v.x*a.x + v.y*a.y + v.z*a.z + v.w*a.w;
    d += __shfl_xor(d,1); d += __shfl_xor(d,2); d += __shfl_xor(d,4);
    d += __shfl_xor(d,8); d += __shfl_xor(d,16);
    if ((tid & 31) == 0) qdp[qi] = d;
  }
  __syncthreads();
  const int lane = tid & 63, wv = tid >> 6, l15 = lane & 15, l4 = lane >> 4;
  uint4* qmf = (uint4*)(wsp + QMF_OFF);
  uint4* qtf = (uint4*)(wsp + QTF_OFF);
  #pragma unroll
  for (int i=0;i<8;i++){
    int f = wv*8 + i;
    int kl = f >> 3, nf = f & 7;
    uint4 u = *(const uint4*)&tm[(nf*16 + l15)*136 + kl*32 + l4*8];
    qmf[(size_t)((b*16 + et*4 + kl)*8 + nf)*64 + lane] = u;
  }
  #pragma unroll
  for (int i=0;i<8;i++){
    int f = wv*8 + i;
    int ks2 = f >> 3, nl = f & 7, ne = et*8 + nl;
    uint32 x[4];
    #pragma unroll
    for (int p=0;p<4;p++){
      u16 t0 = tt[(ks2*32 + l4*8 + 2*p    )*136 + nl*16 + l15];
      u16 t1 = tt[(ks2*32 + l4*8 + 2*p + 1)*136 + nl*16 + l15];
      x[p] = (uint32)t0 | ((uint32)t1 << 16);
    }
    uint4 u; u.x = x[0]; u.y = x[1]; u.z = x[2]; u.w = x[3];
    qtf[(size_t)((b*4 + ks2)*32 + ne)*64 + lane] = u;
  }
}

// ---- main: 256 persistent blocks (1/CU) x 8 waves; block = 128 rows of one batch
// as 8 tiles of 16 rows. qtf resident in LDS (no in-loop DMA). Raw barriers only:
// next-tile ctx loads stay in flight across the whole tile body; stores drain lazily.
__global__ __attribute__((amdgpu_flat_work_group_size(512, 512)))
           __attribute__((amdgpu_waves_per_eu(2)))
void k_main(const float* __restrict__ ctx,
            unsigned char* __restrict__ wsp,
            float* __restrict__ out){
  __shared__ __align__(16) unsigned char qlds[131072]; // qtf[b] resident (128 frags x 1KB)
  __shared__ __align__(16) unsigned char buf[16384];   // ctx tile bf16 [16][512], XOR-swz
  __shared__ __align__(16) unsigned char pfrag[4096];  // P frags [4][1KB]
  __shared__ float mx_s[16*8];
  __shared__ float sm_s[16*8];
  __shared__ float wrow_s[16];
  __shared__ float scale_s;
  __shared__ float Mblk_s, Sblk_s;

  const int bid = blockIdx.x;
  const int sw  = (bid & 7)*32 + (bid >> 3);   // XCD-contiguous: batch fully on one XCD
  const int b   = sw >> 3;
  const int seg = sw & 7;                      // 128-row segment
  const int tid = threadIdx.x;
  const int lane = tid & 63;
  const int w    = tid >> 6;                   // q-slice (GEMM1) / e-slice (GEMM2)
  const int l15  = lane & 15;
  const int l4   = lane >> 4;

  if (tid == 0){ Mblk_s = -3.0e38f; Sblk_s = 0.f; }

  // qtf -> LDS once (completion guaranteed transitively: these are oldest in the
  // in-order vmcnt queue; the compiler's wait on the newer ctx loads drains them)
  const unsigned char* qtfb = wsp + QTF_OFF + (size_t)b*131072;
  #pragma unroll
  for (int j=0;j<16;j++){
    const int f = w*16 + j;
    __builtin_amdgcn_global_load_lds(
      (const __attribute__((address_space(1))) uint32*)(qtfb + (size_t)f*1024 + lane*16),
      (__attribute__((address_space(3))) uint32*)(qlds + f*1024), 16, 0, 0);
  }

  // ctx tile-0 loads (4 float4/thread per 16-row tile)
  const float4* cseg = (const float4*)(ctx + (size_t)(b*CC + seg*128)*EE);
  float4 v[4];
  #pragma unroll
  for (int k=0;k<4;k++) v[k] = cseg[k*512 + tid];

  // qm' A-frags (held all 8 tiles) + qdot
  const uint4* qmf4 = (const uint4*)(wsp + QMF_OFF);
  bf16x8 a[16];
  #pragma unroll
  for (int ks=0;ks<16;ks++)
    a[ks] = __builtin_bit_cast(bf16x8, qmf4[(size_t)((b*16 + ks)*8 + w)*64 + lane]);
  float qdv[4];
  {
    const float* qdp = (const float*)(wsp + QDP_OFF) + (size_t)b*512;
    #pragma unroll
    for (int r=0;r<4;r++){
      const int qi = w*16 + l4*4 + r;
      qdv[r] = qdp[qi] + qdp[128+qi] + qdp[256+qi] + qdp[384+qi];
    }
  }

  float pv = 0.f;
  float* ob_base = out + (size_t)(b*CC + seg*128)*EE;

  #pragma unroll
  for (int i=0;i<8;i++){
    // stage tile i: cvt + ds_write (compiler waits v[] per-use; stores stay in flight)
    {
      const int colb = (tid & 127)*8;
      #pragma unroll
      for (int k=0;k<4;k++){
        const int row = k*4 + (tid >> 7);
        uint2 u;
        u.x = (uint32)bfc(v[k].x) | ((uint32)bfc(v[k].y) << 16);
        u.y = (uint32)bfc(v[k].z) | ((uint32)bfc(v[k].w) << 16);
        *(uint2*)(buf + row*1024 + (colb ^ ((row & 7) << 4))) = u;
      }
    }
    // prefetch tile i+1 — rides in flight through GEMM1/softmax/GEMM2/q2c below
    if (i < 7){
      #pragma unroll
      for (int k=0;k<4;k++) v[k] = cseg[(i+1)*2048 + k*512 + tid];
    }
    RAWBAR();                                  // B1: buf ready (no vmcnt drain)

    // GEMM1: sim[q16][c16] = qm'(regs) x ctx(LDS)
    f32x4 acc = (f32x4){0.f,0.f,0.f,0.f};
    #pragma unroll
    for (int ks=0; ks<16; ks++){
      bf16x8 bf = __builtin_bit_cast(bf16x8,
        *(const uint4*)(buf + l15*1024 + ((ks*64 + l4*16) ^ ((l15 & 7) << 4))));
      acc = __builtin_amdgcn_mfma_f32_16x16x32_bf16(a[ks], bf, acc, 0, 0, 0);
    }

    // softmax (m=0 exp, shift-invariant; |sim|<~10, clamp 80) -> pfrag + stats
    {
      float m = -3.0e38f, s = 0.f;
      u16 hb[4];
      #pragma unroll
      for (int r=0;r<4;r++){
        float vv = fminf(acc[r] + qdv[r], 80.f);
        m = fmaxf(m, vv);
        u16 h = bfc(__expf(vv));
        hb[r] = h;
        s += bf2f(h);
      }
      uint2 u; u.x = (uint32)hb[0] | ((uint32)hb[1]<<16);
               u.y = (uint32)hb[2] | ((uint32)hb[3]<<16);
      *(uint2*)(pfrag + (w>>1)*1024 + (((w&1)*2 + (l4>>1))*16 + l15)*16 + (l4&1)*8) = u;
      m = fmaxf(m, __shfl_xor(m, 16)); m = fmaxf(m, __shfl_xor(m, 32));
      s += __shfl_xor(s, 16);          s += __shfl_xor(s, 32);
      if (l4 == 0){ mx_s[l15*8 + w] = m; sm_s[l15*8 + w] = s; }
    }
    RAWBAR();                                  // B2: pfrag + stats visible

    // rden for this wave's c-rows
    float rden[4];
    #pragma unroll
    for (int r=0;r<4;r++){
      const float* sp = &sm_s[(l4*4 + r)*8];
      rden[r] = 1.f/(sp[0]+sp[1]+sp[2]+sp[3]+sp[4]+sp[5]+sp[6]+sp[7]);
    }
    // P A-frags
    bf16x8 pa[4];
    #pragma unroll
    for (int k2=0;k2<4;k2++)
      pa[k2] = __builtin_bit_cast(bf16x8, *(const uint4*)(pfrag + k2*1024 + lane*16));

    // wave0: per-block online q2c stats (true row maxes from mx_s)
    if (w == 0 && lane < 16){
      const float* mp = &mx_s[lane*8];
      float mf = fmaxf(fmaxf(fmaxf(mp[0],mp[1]),fmaxf(mp[2],mp[3])),
                       fmaxf(fmaxf(mp[4],mp[5]),fmaxf(mp[6],mp[7])));
      float tm = mf;
      tm = fmaxf(tm, __shfl_xor(tm,1)); tm = fmaxf(tm, __shfl_xor(tm,2));
      tm = fmaxf(tm, __shfl_xor(tm,4)); tm = fmaxf(tm, __shfl_xor(tm,8));
      float Mold = Mblk_s;
      float Mnew = fmaxf(Mold, tm);
      float wr = __expf(mf - Mnew);
      wrow_s[lane] = wr;
      float ssum = wr;
      ssum += __shfl_xor(ssum,1); ssum += __shfl_xor(ssum,2);
      ssum += __shfl_xor(ssum,4); ssum += __shfl_xor(ssum,8);
      if (lane == 0){
        float sc = __expf(Mold - Mnew);
        scale_s = sc;
        Sblk_s  = Sblk_s*sc + ssum;
        Mblk_s  = Mnew;
      }
    }

    // GEMM2: c2q[c16][e64] from resident qtf; stores issued, never waited in-loop
    f32x4 acc2[4];
    #pragma unroll
    for (int n=0;n<4;n++) acc2[n] = (f32x4){0.f,0.f,0.f,0.f};
    #pragma unroll
    for (int k2=0;k2<4;k2++){
      #pragma unroll
      for (int n=0;n<4;n++){
        bf16x8 bq = __builtin_bit_cast(bf16x8,
          *(const uint4*)(qlds + (size_t)(k2*32 + w*4 + n)*1024 + lane*16));
        acc2[n] = __builtin_amdgcn_mfma_f32_16x16x32_bf16(pa[k2], bq, acc2[n], 0, 0, 0);
      }
    }
    float* ob = ob_base + (size_t)i*16*EE + w*64;
    #pragma unroll
    for (int n=0;n<4;n++){
      #pragma unroll
      for (int r=0;r<4;r++)
        ob[(size_t)(l4*4 + r)*EE + n*16 + l15] = acc2[n][r]*rden[r];
    }
    RAWBAR();                                  // B3: wrow/scale visible; pfrag reads done

    // q2c online accumulate from LDS bf16 ctx (no global re-read)
    {
      const float sc = scale_s;
      float add = 0.f;
      #pragma unroll
      for (int rr=0; rr<16; rr++){
        uint32 x = *(const u16*)(buf + rr*1024 + ((tid*2) ^ ((rr & 7) << 4)));
        add = fmaf(wrow_s[rr], bf2f(x), add);
      }
      pv = pv*sc + add;
    }
    RAWBAR();                                  // B4: buf free for next stage
  }

  ((float*)(wsp + PVB_OFF))[(size_t)(b*8 + seg)*512 + tid] = pv;
  if (tid == 0){
    ((float*)(wsp + MB_OFF))[b*8 + seg] = Mblk_s;
    ((float*)(wsp + SB_OFF))[b*8 + seg] = Sblk_s;
  }
}

// ---- q2c combine: 8 block-partials per batch ----
__global__ __launch_bounds__(256) void k_fin(unsigned char* __restrict__ wsp,
                                             float* __restrict__ out){
  const int b = blockIdx.x;
  __shared__ float sc_s[8];
  __shared__ float dinv_s;
  const int tid = threadIdx.x;
  if (tid < 8){
    float Mk = ((const float*)(wsp + MB_OFF))[b*8 + tid];
    float Sk = ((const float*)(wsp + SB_OFF))[b*8 + tid];
    float M = Mk;
    M = fmaxf(M, __shfl_xor(M,1)); M = fmaxf(M, __shfl_xor(M,2)); M = fmaxf(M, __shfl_xor(M,4));
    float ev = __expf(Mk - M);
    float d = ev*Sk;
    d += __shfl_xor(d,1); d += __shfl_xor(d,2); d += __shfl_xor(d,4);
    sc_s[tid] = ev;
    if (tid == 0) dinv_s = 1.f/d;
  }
  __syncthreads();
  const float* pvb = (const float*)(wsp + PVB_OFF) + (size_t)b*8*512;
  float a0 = 0.f, a1 = 0.f;
  #pragma unroll
  for (int k=0;k<8;k++){
    float s = sc_s[k];
    a0 = fmaf(s, pvb[k*512 + tid],       a0);
    a1 = fmaf(s, pvb[k*512 + tid + 256], a1);
  }
  size_t base = (size_t)BB*CC*EE + (size_t)b*EE;
  float di = dinv_s;
  out[base + tid]       = a0*di;
  out[base + tid + 256] = a1*di;
}

extern "C" void kernel_launch(void* const* d_in, const int* in_sizes, int n_in,
                              void* d_out, int out_size, void* d_ws, size_t ws_size,
                              hipStream_t stream){
  const float* ctx = (const float*)d_in[0];
  const float* q   = (const float*)d_in[1];
  const float* ws  = (const float*)d_in[2];
  float* out = (float*)d_out;
  unsigned char* wsp = (unsigned char*)d_ws;

  k_prep<<<dim3(BB*4), dim3(256), 0, stream>>>(q, ws, wsp);
  k_main<<<dim3(256),  dim3(512), 0, stream>>>(ctx, wsp, out);
  k_fin <<<dim3(BB),   dim3(256), 0, stream>>>(wsp, out);
}

// Round 10
// 53.557 us; speedup vs baseline: 2.0210x; 2.0210x over previous
//
#include <hip/hip_runtime.h>

#define BB 32
#define CC 1024
#define QQ 128
#define EE 512

typedef unsigned int uint32;
typedef unsigned short u16;
typedef __bf16 bf16x8 __attribute__((ext_vector_type(8)));
typedef float f32x4 __attribute__((ext_vector_type(4)));

// workspace layout (bytes), total ~19MB
#define QMF_OFF  (0u)                        // bf16 frag-major: [b][ks16][nf8][lane][8] (qm' = q*ws_m + ws_c)
#define QTF_OFF  (4u<<20)                    // bf16 frag-major: [b][ks2 4][ne32][lane][8]
#define QDP_OFF  (8u<<20)                    // f32 [b][et4][128] qdot partials (64KB)
#define RDEN_OFF ((8u<<20)+(1u<<16))         // f32 [b][1024] softmax 1/denominator (128KB)
#define MB_OFF   ((8u<<20)+(3u<<16))         // f32 [b][32] tile max
#define SB_OFF   ((8u<<20)+(3u<<16)+4096u)   // f32 [b][32] tile expsum
#define PVB_OFF  ((8u<<20)+(4u<<16))         // f32 [b][32][512] q2c partial (2MB)
#define P_OFF    (11u<<20)                   // bf16 P frags: [b][g64][ks2 4][lane][8] (8MB)

__device__ __forceinline__ u16 bfc(float f){
  __bf16 h = (__bf16)f;                // HW v_cvt (RNE)
  return __builtin_bit_cast(u16, h);
}
__device__ __forceinline__ float bf2f(uint32 lo16){
  return __builtin_bit_cast(float, lo16 << 16);
}

// ---- fused prep: per (b, e-slice et): qm' frags + qt frags + qdot partial ----
__global__ __launch_bounds__(256) void k_prep(const float* __restrict__ q,
                                              const float* __restrict__ ws,
                                              unsigned char* __restrict__ wsp){
  const int b = blockIdx.x >> 2, et = blockIdx.x & 3, e0 = et*128;
  __shared__ u16 tm[128*136];          // qm' = q*ws_m + ws_c (bf16)
  __shared__ u16 tt[128*136];          // raw q (bf16)
  const int tid = threadIdx.x;
  float* qdp = (float*)(wsp + QDP_OFF) + (size_t)(b*4 + et)*128;
  #pragma unroll
  for (int i=0;i<16;i++){
    int id = tid + i*256;
    int qi = id >> 5;
    int el = (id & 31) << 2;
    float4 v = *(const float4*)(q + (size_t)(b*QQ+qi)*EE + e0 + el);
    float4 a = *(const float4*)(ws +          e0 + el);
    float4 c = *(const float4*)(ws +   EE +   e0 + el);
    float4 m = *(const float4*)(ws + 2*EE +   e0 + el);
    ushort4 um; um.x = bfc(v.x*m.x + c.x); um.y = bfc(v.y*m.y + c.y);
                um.z = bfc(v.z*m.z + c.z); um.w = bfc(v.w*m.w + c.w);
    *(ushort4*)&tm[qi*136 + el] = um;
    ushort4 ut; ut.x = bfc(v.x); ut.y = bfc(v.y); ut.z = bfc(v.z); ut.w = bfc(v.w);
    *(ushort4*)&tt[qi*136 + el] = ut;
    float d = v.x*a.x + v.y*a.y + v.z*a.z + v.w*a.w;
    d += __shfl_xor(d,1); d += __shfl_xor(d,2); d += __shfl_xor(d,4);
    d += __shfl_xor(d,8); d += __shfl_xor(d,16);
    if ((tid & 31) == 0) qdp[qi] = d;
  }
  __syncthreads();
  const int lane = tid & 63, wv = tid >> 6, l15 = lane & 15, l4 = lane >> 4;
  uint4* qmf = (uint4*)(wsp + QMF_OFF);
  uint4* qtf = (uint4*)(wsp + QTF_OFF);
  #pragma unroll
  for (int i=0;i<8;i++){
    int f = wv*8 + i;
    int kl = f >> 3, nf = f & 7;
    uint4 u = *(const uint4*)&tm[(nf*16 + l15)*136 + kl*32 + l4*8];
    qmf[(size_t)((b*16 + et*4 + kl)*8 + nf)*64 + lane] = u;
  }
  #pragma unroll
  for (int i=0;i<8;i++){
    int f = wv*8 + i;
    int ks2 = f >> 3, nl = f & 7, ne = et*8 + nl;
    uint32 x[4];
    #pragma unroll
    for (int p=0;p<4;p++){
      u16 t0 = tt[(ks2*32 + l4*8 + 2*p    )*136 + nl*16 + l15];
      u16 t1 = tt[(ks2*32 + l4*8 + 2*p + 1)*136 + nl*16 + l15];
      x[p] = (uint32)t0 | ((uint32)t1 << 16);
    }
    uint4 u; u.x = x[0]; u.y = x[1]; u.z = x[2]; u.w = x[3];
    qtf[(size_t)((b*4 + ks2)*32 + ne)*64 + lane] = u;
  }
}

// ---- k_sim: READ-bound. 1024 blocks (b x 32-row tile) x 8 waves.
// ctx tile -> LDS bf16; flipped GEMM1 (qm' regs x ctx LDS); m=0 softmax;
// P bf16 frags -> workspace (L3); rden, q2c tile stats + PV partial. 3 barriers.
__global__ __launch_bounds__(512, 4) void k_sim(const float* __restrict__ ctx,
                                                unsigned char* __restrict__ wsp){
  __shared__ __align__(16) unsigned char buf[32768]; // ctx bf16 [32][512] XOR-swz
  __shared__ float mx_s[32*8];
  __shared__ float sm_s[32*8];
  __shared__ float wrow_s[32];

  const int bid = blockIdx.x;
  const int sw  = (bid & 7)*128 + (bid >> 3);  // XCD-contiguous (1024%8==0)
  const int b   = sw >> 5;
  const int t   = sw & 31;
  const int tid = threadIdx.x;
  const int lane = tid & 63;
  const int w    = tid >> 6;                   // q-16-group
  const int l15  = lane & 15;
  const int l4   = lane >> 4;

  // ctx tile loads first (HBM long-pole)
  const float4* cb4 = (const float4*)(ctx + (size_t)(b*CC + t*32)*EE);
  float4 v[8];
  #pragma unroll
  for (int i=0;i<8;i++) v[i] = cb4[i*512 + tid];

  // qm' A-frags (L2-hot) + qdot
  const uint4* qmf4 = (const uint4*)(wsp + QMF_OFF);
  bf16x8 a[16];
  #pragma unroll
  for (int ks=0;ks<16;ks++)
    a[ks] = __builtin_bit_cast(bf16x8, qmf4[(size_t)((b*16 + ks)*8 + w)*64 + lane]);
  float qdv[4];
  {
    const float* qdp = (const float*)(wsp + QDP_OFF) + (size_t)b*512;
    #pragma unroll
    for (int r=0;r<4;r++){
      const int qi = w*16 + l4*4 + r;
      qdv[r] = qdp[qi] + qdp[128+qi] + qdp[256+qi] + qdp[384+qi];
    }
  }

  // stage: cvt + ds_write (XOR-swz 16B slots)
  {
    const int colb = (tid & 127)*8;
    #pragma unroll
    for (int i=0;i<8;i++){
      const int row = i*4 + (tid >> 7);
      uint2 u;
      u.x = (uint32)bfc(v[i].x) | ((uint32)bfc(v[i].y) << 16);
      u.y = (uint32)bfc(v[i].z) | ((uint32)bfc(v[i].w) << 16);
      *(uint2*)(buf + row*1024 + (colb ^ ((row & 7) << 4))) = u;
    }
  }
  __syncthreads();                             // buf ready

  // GEMM1: sim[q16][c32] = qm'(regs) x ctx(LDS)
  f32x4 acc[2];
  acc[0] = (f32x4){0.f,0.f,0.f,0.f};
  acc[1] = (f32x4){0.f,0.f,0.f,0.f};
  #pragma unroll
  for (int ks=0; ks<16; ks++){
    #pragma unroll
    for (int cc=0; cc<2; cc++){
      const int row = cc*16 + l15;
      bf16x8 bf = __builtin_bit_cast(bf16x8,
        *(const uint4*)(buf + row*1024 + ((ks*64 + l4*16) ^ ((row & 7) << 4))));
      acc[cc] = __builtin_amdgcn_mfma_f32_16x16x32_bf16(a[ks], bf, acc[cc], 0, 0, 0);
    }
  }

  // softmax (m=0 exp, shift-invariant, clamp 80): P frags -> global, sums -> LDS
  {
    unsigned char* pgb = wsp + P_OFF
      + ((size_t)(b*64 + t*2)*4 + (w>>1))*1024
      + (((2*w + (l4>>1)) & 3)*16 + l15)*16 + (l4&1)*8;
    #pragma unroll
    for (int cc=0; cc<2; cc++){
      float m = -3.0e38f, s = 0.f;
      u16 hb[4];
      #pragma unroll
      for (int r=0;r<4;r++){
        float vv = fminf(acc[cc][r] + qdv[r], 80.f);
        m = fmaxf(m, vv);
        u16 h = bfc(__expf(vv));
        hb[r] = h;
        s += bf2f(h);
      }
      uint2 u; u.x = (uint32)hb[0] | ((uint32)hb[1]<<16);
               u.y = (uint32)hb[2] | ((uint32)hb[3]<<16);
      *(uint2*)(pgb + cc*4096) = u;
      m = fmaxf(m, __shfl_xor(m, 16)); m = fmaxf(m, __shfl_xor(m, 32));
      s += __shfl_xor(s, 16);          s += __shfl_xor(s, 32);
      if (l4 == 0){
        mx_s[(cc*16 + l15)*8 + w] = m;
        sm_s[(cc*16 + l15)*8 + w] = s;
      }
    }
  }
  __syncthreads();                             // stats visible

  // rden + q2c tile stats (lanes 0..31 of wave 0)
  if (tid < 32){
    const float* sp = &sm_s[tid*8];
    float sum = sp[0]+sp[1]+sp[2]+sp[3]+sp[4]+sp[5]+sp[6]+sp[7];
    ((float*)(wsp + RDEN_OFF))[b*1024 + t*32 + tid] = 1.f/sum;
    const float* mp = &mx_s[tid*8];
    float mf = fmaxf(fmaxf(fmaxf(mp[0],mp[1]),fmaxf(mp[2],mp[3])),
                     fmaxf(fmaxf(mp[4],mp[5]),fmaxf(mp[6],mp[7])));
    float M = mf;
    M = fmaxf(M, __shfl_xor(M,1)); M = fmaxf(M, __shfl_xor(M,2));
    M = fmaxf(M, __shfl_xor(M,4)); M = fmaxf(M, __shfl_xor(M,8));
    M = fmaxf(M, __shfl_xor(M,16));
    float wr = __expf(mf - M);
    wrow_s[tid] = wr;
    float S = wr;
    S += __shfl_xor(S,1); S += __shfl_xor(S,2); S += __shfl_xor(S,4);
    S += __shfl_xor(S,8); S += __shfl_xor(S,16);
    if (tid == 0){
      ((float*)(wsp + MB_OFF))[b*32 + t] = M;
      ((float*)(wsp + SB_OFF))[b*32 + t] = S;
    }
  }
  __syncthreads();                             // wrow visible

  // q2c PV partial from LDS bf16 ctx (thread owns e=tid)
  {
    float pv = 0.f;
    #pragma unroll
    for (int rr=0; rr<32; rr++){
      uint32 x = *(const u16*)(buf + rr*1024 + ((tid*2) ^ ((rr & 7) << 4)));
      pv = fmaf(wrow_s[rr], bf2f(x), pv);
    }
    ((float*)(wsp + PVB_OFF))[(size_t)(b*32 + t)*512 + tid] = pv;
  }
}

// ---- k_out: WRITE-bound. 2048 blocks (b x 64-row x 128-e tile) x 4 waves.
// P frags (L3) x qtf (LDS via DMA) -> 64MB out. One barrier.
__global__ __launch_bounds__(256, 4) void k_out(unsigned char* __restrict__ wsp,
                                                float* __restrict__ out){
  __shared__ __align__(16) unsigned char qts[32768]; // qtf slice [ks2 4][ne 8][1KB]

  const int bid = blockIdx.x;
  const int sw  = (bid & 7)*256 + (bid >> 3);  // XCD-contiguous (2048%8==0)
  const int b   = sw >> 6;
  const int rr  = sw & 63;
  const int ct  = rr >> 2;                     // 64-row tile (0..15)
  const int et  = rr & 3;                      // 128-e tile
  const int tid = threadIdx.x;
  const int lane = tid & 63;
  const int w    = tid >> 6;                   // c-16-group within tile
  const int l15  = lane & 15;
  const int l4   = lane >> 4;

  // DMA qtf slice: wave w loads ks2=w's 8 ne-frags (8KB)
  const unsigned char* qtfb = wsp + QTF_OFF + (size_t)b*131072;
  #pragma unroll
  for (int j=0;j<8;j++){
    __builtin_amdgcn_global_load_lds(
      (const __attribute__((address_space(1))) uint32*)
        (qtfb + (size_t)(w*32 + et*8 + j)*1024 + lane*16),
      (__attribute__((address_space(3))) uint32*)(qts + (w*8 + j)*1024), 16, 0, 0);
  }

  // P A-frags (L3-hot) + rden
  bf16x8 pa[4];
  #pragma unroll
  for (int k2=0;k2<4;k2++)
    pa[k2] = __builtin_bit_cast(bf16x8,
      *(const uint4*)(wsp + P_OFF + ((size_t)(b*64 + ct*4 + w)*4 + k2)*1024 + lane*16));
  float rden[4];
  {
    const float* rg = (const float*)(wsp + RDEN_OFF) + b*1024 + ct*64 + w*16;
    #pragma unroll
    for (int r=0;r<4;r++) rden[r] = rg[l4*4 + r];
  }
  __syncthreads();                             // DMA landed

  f32x4 acc2[8];
  #pragma unroll
  for (int n=0;n<8;n++) acc2[n] = (f32x4){0.f,0.f,0.f,0.f};
  #pragma unroll
  for (int k2=0;k2<4;k2++){
    #pragma unroll
    for (int n=0;n<8;n++){
      bf16x8 bq = __builtin_bit_cast(bf16x8,
        *(const uint4*)(qts + (k2*8 + n)*1024 + lane*16));
      acc2[n] = __builtin_amdgcn_mfma_f32_16x16x32_bf16(pa[k2], bq, acc2[n], 0, 0, 0);
    }
  }

  float* ob = out + (size_t)(b*CC + ct*64 + w*16)*EE + et*128;
  #pragma unroll
  for (int n=0;n<8;n++){
    #pragma unroll
    for (int r=0;r<4;r++)
      ob[(size_t)(l4*4 + r)*EE + n*16 + l15] = acc2[n][r]*rden[r];
  }
}

// ---- q2c combine: 32 tile-partials per batch ----
__global__ __launch_bounds__(256) void k_fin(unsigned char* __restrict__ wsp,
                                             float* __restrict__ out){
  const int b = blockIdx.x;
  __shared__ float sc_s[32];
  __shared__ float dinv_s;
  const int tid = threadIdx.x;
  if (tid < 32){
    float Mk = ((const float*)(wsp + MB_OFF))[b*32 + tid];
    float Sk = ((const float*)(wsp + SB_OFF))[b*32 + tid];
    float M = Mk;
    M = fmaxf(M, __shfl_xor(M,1)); M = fmaxf(M, __shfl_xor(M,2));
    M = fmaxf(M, __shfl_xor(M,4)); M = fmaxf(M, __shfl_xor(M,8));
    M = fmaxf(M, __shfl_xor(M,16));
    float ev = __expf(Mk - M);
    float d = ev*Sk;
    d += __shfl_xor(d,1); d += __shfl_xor(d,2); d += __shfl_xor(d,4);
    d += __shfl_xor(d,8); d += __shfl_xor(d,16);
    sc_s[tid] = ev;
    if (tid == 0) dinv_s = 1.f/d;
  }
  __syncthreads();
  const float* pvb = (const float*)(wsp + PVB_OFF) + (size_t)b*32*512;
  float a0 = 0.f, a1 = 0.f;
  #pragma unroll
  for (int k=0;k<32;k++){
    float s = sc_s[k];
    a0 = fmaf(s, pvb[k*512 + tid],       a0);
    a1 = fmaf(s, pvb[k*512 + tid + 256], a1);
  }
  size_t base = (size_t)BB*CC*EE + (size_t)b*EE;
  float di = dinv_s;
  out[base + tid]       = a0*di;
  out[base + tid + 256] = a1*di;
}

extern "C" void kernel_launch(void* const* d_in, const int* in_sizes, int n_in,
                              void* d_out, int out_size, void* d_ws, size_t ws_size,
                              hipStream_t stream){
  const float* ctx = (const float*)d_in[0];
  const float* q   = (const float*)d_in[1];
  const float* ws  = (const float*)d_in[2];
  float* out = (float*)d_out;
  unsigned char* wsp = (unsigned char*)d_ws;

  k_prep<<<dim3(BB*4), dim3(256), 0, stream>>>(q, ws, wsp);
  k_sim <<<dim3(1024), dim3(512), 0, stream>>>(ctx, wsp);
  k_out <<<dim3(2048), dim3(256), 0, stream>>>(wsp, out);
  k_fin <<<dim3(BB),   dim3(256), 0, stream>>>(wsp, out);
}